// Round 14
// baseline (119.262 us; speedup 1.0000x reference)
//
#include <hip/hip_runtime.h>

#define NN 50000
#define NE 800000
#define ND 1000000
#define DH 128
#define DO 64

#define NB 196          // buckets: bucket = dst >> 8 (256 nodes each)
#define BCAP 5120       // per-bucket capacity (mean 4096, sd ~64 -> 16 sigma)
#define P1B 196         // pass-1 edge blocks (1024 thr x 4 edges = 4096)
#define WTB1 24         // transpose blocks (1024 thr): (16384+8192)/1024
#define GB1 ((NN + 63) / 64)   // 782 gemm blocks

typedef _Float16 h16;
typedef h16 h16x4 __attribute__((ext_vector_type(4)));
typedef h16 h16x8 __attribute__((ext_vector_type(8)));
typedef float f32x4 __attribute__((ext_vector_type(4)));
typedef int i32x4 __attribute__((ext_vector_type(4)));
typedef unsigned short u16;

// Pass 1: bucket edges by dst>>8 (packed src|dlow<<16) || W transpose.
__global__ __launch_bounds__(1024) void k_bucket_wt(
    const int* __restrict__ esrc, const int* __restrict__ edst,
    int* __restrict__ bpk, int* __restrict__ bcur,
    const float* __restrict__ Wi, const float* __restrict__ Wo,
    h16* __restrict__ WiT, h16* __restrict__ WoT) {
    if (blockIdx.x < P1B) {
        __shared__ int hist[NB], gbase[NB], lcur[NB];
        int t = threadIdx.x;
        if (t < NB) { hist[t] = 0; lcur[t] = 0; }
        __syncthreads();
        int base = blockIdx.x * 4096;
        int b[4], pk[4];
#pragma unroll
        for (int i = 0; i < 4; ++i) {
            int idx = base + t + i * 1024;
            if (idx < NE) {
                int s = esrc[idx];
                int d = edst[idx];
                b[i] = d >> 8;
                pk[i] = s | ((d & 255) << 16);
                atomicAdd(&hist[b[i]], 1);
            } else {
                b[i] = -1;
            }
        }
        __syncthreads();
        if (t < NB && hist[t] > 0) gbase[t] = atomicAdd(&bcur[t], hist[t]);
        __syncthreads();
#pragma unroll
        for (int i = 0; i < 4; ++i) {
            if (b[i] >= 0) {
                int r = atomicAdd(&lcur[b[i]], 1);
                bpk[b[i] * BCAP + gbase[b[i]] + r] = pk[i];
            }
        }
    } else {
        int t = (blockIdx.x - P1B) * 1024 + threadIdx.x;
        if (t < 128 * 128) {            // WiT[n][k] = Wi[k][n]
            int k = t >> 7, n = t & 127;
            WiT[n * 128 + k] = (h16)Wi[t];
        } else {                        // WoT[n][k] = Wo[k][n]
            int t2 = t - 128 * 128;     // < 8192
            int k = t2 >> 6, n = t2 & 63;
            WoT[n * 128 + k] = (h16)Wo[t2];
        }
    }
}

// ---------------- MFMA GEMM body (NO dinv dependency) ----------------
template <int BN, bool AF32>
__device__ __forceinline__ void gemm_body(
    const void* __restrict__ Ain, const h16* __restrict__ WT,
    h16* __restrict__ out, int bx, char* sX, char* sW) {
    const int tid = threadIdx.x;
    const int row0 = bx * 64;

#pragma unroll
    for (int i = 0; i < 4; ++i) {
        int c = tid + i * 256;
        int row = c >> 4, kb = c & 15;
        int gr = row0 + row;
        h16x8 v = {};
        if (gr < NN) {
            if (AF32) {
                const float* src = (const float*)Ain + (size_t)gr * 128 + kb * 8;
                float4 u0 = *(const float4*)src;
                float4 u1 = *(const float4*)(src + 4);
                v[0] = (h16)u0.x; v[1] = (h16)u0.y; v[2] = (h16)u0.z; v[3] = (h16)u0.w;
                v[4] = (h16)u1.x; v[5] = (h16)u1.y; v[6] = (h16)u1.z; v[7] = (h16)u1.w;
            } else {
                v = *(const h16x8*)((const h16*)Ain + (size_t)gr * 128 + kb * 8);
            }
        }
        *(h16x8*)(sX + row * 256 + ((kb * 16) ^ ((row & 7) << 4))) = v;
    }
#pragma unroll
    for (int i = 0; i < BN / 16; ++i) {
        int c = tid + i * 256;
        int n = c >> 4, kb = c & 15;
        h16x8 v = *(const h16x8*)&WT[(size_t)n * 128 + kb * 8];
        *(h16x8*)(sW + n * 256 + ((kb * 16) ^ ((n & 7) << 4))) = v;
    }
    __syncthreads();

    const int lane = tid & 63, wv = tid >> 6;
    const int g = lane >> 4, l15 = lane & 15;
    const int r = wv * 16 + l15;
    f32x4 acc[BN / 16];
#pragma unroll
    for (int ct = 0; ct < BN / 16; ++ct) acc[ct] = (f32x4){0.f, 0.f, 0.f, 0.f};

#pragma unroll
    for (int t = 0; t < 4; ++t) {
        int kb2 = t * 64 + g * 16;
        h16x8 a = *(const h16x8*)(sX + r * 256 + (kb2 ^ ((r & 7) << 4)));
#pragma unroll
        for (int ct = 0; ct < BN / 16; ++ct) {
            int n = ct * 16 + l15;
            h16x8 b = *(const h16x8*)(sW + n * 256 + (kb2 ^ ((n & 7) << 4)));
            acc[ct] = __builtin_amdgcn_mfma_f32_16x16x32_f16(a, b, acc[ct], 0, 0, 0);
        }
    }

#pragma unroll
    for (int j = 0; j < 4; ++j) {
        int row = row0 + wv * 16 + g * 4 + j;
        if (row < NN) {
#pragma unroll
            for (int ct = 0; ct < BN / 16; ++ct)
                out[(size_t)row * BN + ct * 16 + l15] = (h16)acc[ct][j];
        }
    }
}

// Fused: {per-bucket counting sort (blocks 0..NB-1)} || {gemm1 x*Wi unscaled}.
// Dep check: gemm reads {x,WiT} writes h1; sort reads {bpk,bcur} writes
// {off,degn,dinv,csrc}. Disjoint -> race-free.
__global__ __launch_bounds__(256) void k_sort_gemm1(
    const int* __restrict__ bpk, const int* __restrict__ bcur,
    int* __restrict__ gcur, int* __restrict__ off, int* __restrict__ degn,
    float* __restrict__ dinv, u16* __restrict__ csrc,
    const float* __restrict__ x, const h16* __restrict__ WiT,
    h16* __restrict__ h1) {
    __shared__ __align__(16) char smem[49152];
    if (blockIdx.x >= NB) {
        gemm_body<DH, true>(x, WiT, h1, blockIdx.x - NB, smem, smem + 16384);
        return;
    }
    int* hist = (int*)smem;          // 256
    int* lofs = hist + 256;          // 256
    int* exc  = lofs + 256;          // 256
    int* lcur = exc + 256;           // 256
    int* sgb  = lcur + 256;          // 1
    u16* scsr = (u16*)(sgb + 4);     // BCAP+2
    int b = blockIdx.x, t = threadIdx.x;
    hist[t] = 0; lcur[t] = 0;
    __syncthreads();
    int cnt = bcur[b];
    if (t == 0) *sgb = atomicAdd(gcur, (cnt + 1) & ~1);  // even base
    const int* bp = bpk + b * BCAP;
    for (int j = t; j < cnt; j += 256)
        atomicAdd(&hist[(bp[j] >> 16) & 255], 1);
    __syncthreads();
    lofs[t] = hist[t];
    __syncthreads();
#pragma unroll
    for (int d = 1; d < 256; d <<= 1) {
        int add = (t >= d) ? lofs[t - d] : 0;
        __syncthreads();
        lofs[t] += add;
        __syncthreads();
    }
    exc[t] = lofs[t] - hist[t];
    __syncthreads();
    int gbase = *sgb;
    int node = b * 256 + t;
    if (node < NN) {
        off[node] = gbase + exc[t];
        degn[node] = hist[t];
        dinv[node] = rsqrtf((float)hist[t] + 1.0f);  // +1 self-loop
    }
    for (int j = t; j < cnt; j += 256) {
        int p = bp[j];
        int d = (p >> 16) & 255;
        int r = atomicAdd(&lcur[d], 1);
        scsr[exc[d] + r] = (u16)(p & 0xFFFF);
    }
    __syncthreads();
    if (t == 0 && (cnt & 1)) scsr[cnt] = 0;  // pad slot (never read)
    __syncthreads();
    int cpairs = (cnt + 1) >> 1;
    u16* cdst = csrc + gbase;
    for (int j = t; j < cpairs; j += 256)
        *(unsigned*)(cdst + 2 * j) = *(const unsigned*)(scsr + 2 * j);
}

__global__ __launch_bounds__(256) void k_gemm2(
    const h16* __restrict__ z1, const h16* __restrict__ WoT,
    h16* __restrict__ h2) {
    __shared__ __align__(16) char smem[32768];
    gemm_body<DO, false>(z1, WoT, h2, blockIdx.x, smem, smem + 16384);
}

// z1[n] = fp16(relu(dinv[n]*(sum dinv[s]*h1[s] + dinv[n]*h1[n]) + b))
// 32-lane group/node; z1 store is NON-TEMPORAL (protect h1 table in L2).
__global__ __launch_bounds__(256) void k_agg128(
    const h16x4* __restrict__ hs, const float* __restrict__ dinv,
    const int* __restrict__ off, const int* __restrict__ degn,
    const u16* __restrict__ csrc,
    const float* __restrict__ bias, h16x4* __restrict__ z) {
    int node = blockIdx.x * 8 + (threadIdx.x >> 5);
    if (node >= NN) return;
    int col = threadIdx.x & 31;
    int s = off[node], e = s + degn[node];
    float a0 = 0.f, a1 = 0.f, a2 = 0.f, a3 = 0.f;
    int j = s;
    for (; j + 8 <= e; j += 8) {
        int i0 = csrc[j],     i1 = csrc[j + 1], i2 = csrc[j + 2], i3 = csrc[j + 3];
        int i4 = csrc[j + 4], i5 = csrc[j + 5], i6 = csrc[j + 6], i7 = csrc[j + 7];
        float w0 = dinv[i0], w1 = dinv[i1], w2 = dinv[i2], w3 = dinv[i3];
        float w4 = dinv[i4], w5 = dinv[i5], w6 = dinv[i6], w7 = dinv[i7];
        h16x4 v0 = hs[(size_t)i0 * 32 + col];
        h16x4 v1 = hs[(size_t)i1 * 32 + col];
        h16x4 v2 = hs[(size_t)i2 * 32 + col];
        h16x4 v3 = hs[(size_t)i3 * 32 + col];
        h16x4 v4 = hs[(size_t)i4 * 32 + col];
        h16x4 v5 = hs[(size_t)i5 * 32 + col];
        h16x4 v6 = hs[(size_t)i6 * 32 + col];
        h16x4 v7 = hs[(size_t)i7 * 32 + col];
        a0 = fmaf(w0, (float)v0.x, a0); a1 = fmaf(w0, (float)v0.y, a1);
        a2 = fmaf(w0, (float)v0.z, a2); a3 = fmaf(w0, (float)v0.w, a3);
        a0 = fmaf(w1, (float)v1.x, a0); a1 = fmaf(w1, (float)v1.y, a1);
        a2 = fmaf(w1, (float)v1.z, a2); a3 = fmaf(w1, (float)v1.w, a3);
        a0 = fmaf(w2, (float)v2.x, a0); a1 = fmaf(w2, (float)v2.y, a1);
        a2 = fmaf(w2, (float)v2.z, a2); a3 = fmaf(w2, (float)v2.w, a3);
        a0 = fmaf(w3, (float)v3.x, a0); a1 = fmaf(w3, (float)v3.y, a1);
        a2 = fmaf(w3, (float)v3.z, a2); a3 = fmaf(w3, (float)v3.w, a3);
        a0 = fmaf(w4, (float)v4.x, a0); a1 = fmaf(w4, (float)v4.y, a1);
        a2 = fmaf(w4, (float)v4.z, a2); a3 = fmaf(w4, (float)v4.w, a3);
        a0 = fmaf(w5, (float)v5.x, a0); a1 = fmaf(w5, (float)v5.y, a1);
        a2 = fmaf(w5, (float)v5.z, a2); a3 = fmaf(w5, (float)v5.w, a3);
        a0 = fmaf(w6, (float)v6.x, a0); a1 = fmaf(w6, (float)v6.y, a1);
        a2 = fmaf(w6, (float)v6.z, a2); a3 = fmaf(w6, (float)v6.w, a3);
        a0 = fmaf(w7, (float)v7.x, a0); a1 = fmaf(w7, (float)v7.y, a1);
        a2 = fmaf(w7, (float)v7.z, a2); a3 = fmaf(w7, (float)v7.w, a3);
    }
    for (; j < e; ++j) {
        int i = csrc[j];
        float w = dinv[i];
        h16x4 v = hs[(size_t)i * 32 + col];
        a0 = fmaf(w, (float)v.x, a0); a1 = fmaf(w, (float)v.y, a1);
        a2 = fmaf(w, (float)v.z, a2); a3 = fmaf(w, (float)v.w, a3);
    }
    float dv = dinv[node];
    h16x4 vs = hs[(size_t)node * 32 + col];  // self loop
    a0 = fmaf(dv, (float)vs.x, a0); a1 = fmaf(dv, (float)vs.y, a1);
    a2 = fmaf(dv, (float)vs.z, a2); a3 = fmaf(dv, (float)vs.w, a3);
    float4 bb = ((const float4*)bias)[col];
    float r0 = dv * a0 + bb.x, r1 = dv * a1 + bb.y;
    float r2 = dv * a2 + bb.z, r3 = dv * a3 + bb.w;
    h16x4 o;
    o.x = (h16)(r0 > 0.f ? r0 : 0.f); o.y = (h16)(r1 > 0.f ? r1 : 0.f);
    o.z = (h16)(r2 > 0.f ? r2 : 0.f); o.w = (h16)(r3 > 0.f ? r3 : 0.f);
    __builtin_nontemporal_store(o, &z[(size_t)node * 32 + col]);
}

// z2[n] = fp16(relu(...)); 16-lane group/node; z2 store NON-TEMPORAL.
__global__ __launch_bounds__(256) void k_agg64(
    const h16x4* __restrict__ hs, const float* __restrict__ dinv,
    const int* __restrict__ off, const int* __restrict__ degn,
    const u16* __restrict__ csrc,
    const float* __restrict__ bias, h16x4* __restrict__ z) {
    int node = blockIdx.x * 16 + (threadIdx.x >> 4);
    if (node >= NN) return;
    int col = threadIdx.x & 15;
    int s = off[node], e = s + degn[node];
    float a0 = 0.f, a1 = 0.f, a2 = 0.f, a3 = 0.f;
    int j = s;
    for (; j + 8 <= e; j += 8) {
        int i0 = csrc[j],     i1 = csrc[j + 1], i2 = csrc[j + 2], i3 = csrc[j + 3];
        int i4 = csrc[j + 4], i5 = csrc[j + 5], i6 = csrc[j + 6], i7 = csrc[j + 7];
        float w0 = dinv[i0], w1 = dinv[i1], w2 = dinv[i2], w3 = dinv[i3];
        float w4 = dinv[i4], w5 = dinv[i5], w6 = dinv[i6], w7 = dinv[i7];
        h16x4 v0 = hs[(size_t)i0 * 16 + col];
        h16x4 v1 = hs[(size_t)i1 * 16 + col];
        h16x4 v2 = hs[(size_t)i2 * 16 + col];
        h16x4 v3 = hs[(size_t)i3 * 16 + col];
        h16x4 v4 = hs[(size_t)i4 * 16 + col];
        h16x4 v5 = hs[(size_t)i5 * 16 + col];
        h16x4 v6 = hs[(size_t)i6 * 16 + col];
        h16x4 v7 = hs[(size_t)i7 * 16 + col];
        a0 = fmaf(w0, (float)v0.x, a0); a1 = fmaf(w0, (float)v0.y, a1);
        a2 = fmaf(w0, (float)v0.z, a2); a3 = fmaf(w0, (float)v0.w, a3);
        a0 = fmaf(w1, (float)v1.x, a0); a1 = fmaf(w1, (float)v1.y, a1);
        a2 = fmaf(w1, (float)v1.z, a2); a3 = fmaf(w1, (float)v1.w, a3);
        a0 = fmaf(w2, (float)v2.x, a0); a1 = fmaf(w2, (float)v2.y, a1);
        a2 = fmaf(w2, (float)v2.z, a2); a3 = fmaf(w2, (float)v2.w, a3);
        a0 = fmaf(w3, (float)v3.x, a0); a1 = fmaf(w3, (float)v3.y, a1);
        a2 = fmaf(w3, (float)v3.z, a2); a3 = fmaf(w3, (float)v3.w, a3);
        a0 = fmaf(w4, (float)v4.x, a0); a1 = fmaf(w4, (float)v4.y, a1);
        a2 = fmaf(w4, (float)v4.z, a2); a3 = fmaf(w4, (float)v4.w, a3);
        a0 = fmaf(w5, (float)v5.x, a0); a1 = fmaf(w5, (float)v5.y, a1);
        a2 = fmaf(w5, (float)v5.z, a2); a3 = fmaf(w5, (float)v5.w, a3);
        a0 = fmaf(w6, (float)v6.x, a0); a1 = fmaf(w6, (float)v6.y, a1);
        a2 = fmaf(w6, (float)v6.z, a2); a3 = fmaf(w6, (float)v6.w, a3);
        a0 = fmaf(w7, (float)v7.x, a0); a1 = fmaf(w7, (float)v7.y, a1);
        a2 = fmaf(w7, (float)v7.z, a2); a3 = fmaf(w7, (float)v7.w, a3);
    }
    for (; j < e; ++j) {
        int i = csrc[j];
        float w = dinv[i];
        h16x4 v = hs[(size_t)i * 16 + col];
        a0 = fmaf(w, (float)v.x, a0); a1 = fmaf(w, (float)v.y, a1);
        a2 = fmaf(w, (float)v.z, a2); a3 = fmaf(w, (float)v.w, a3);
    }
    float dv = dinv[node];
    h16x4 vs = hs[(size_t)node * 16 + col];  // self loop
    a0 = fmaf(dv, (float)vs.x, a0); a1 = fmaf(dv, (float)vs.y, a1);
    a2 = fmaf(dv, (float)vs.z, a2); a3 = fmaf(dv, (float)vs.w, a3);
    float4 bb = ((const float4*)bias)[col];
    float r0 = dv * a0 + bb.x, r1 = dv * a1 + bb.y;
    float r2 = dv * a2 + bb.z, r3 = dv * a3 + bb.w;
    h16x4 o;
    o.x = (h16)(r0 > 0.f ? r0 : 0.f); o.y = (h16)(r1 > 0.f ? r1 : 0.f);
    o.z = (h16)(r2 > 0.f ? r2 : 0.f); o.w = (h16)(r3 > 0.f ? r3 : 0.f);
    __builtin_nontemporal_store(o, &z[(size_t)node * 16 + col]);
}

// 8-lane groups, h16x8 loads, 8 pairs/group. eli loads + out stores are
// NON-TEMPORAL (protect the z2 gather table in L2).
__global__ __launch_bounds__(256) void k_dec(const h16* __restrict__ z2,
                                             const int* __restrict__ eli,
                                             float* __restrict__ out) {
    int g = blockIdx.x * 32 + (threadIdx.x >> 3);
    int p0 = g * 8;
    if (p0 >= ND) return;
    int sub = threadIdx.x & 7;
    i32x4 ea0 = __builtin_nontemporal_load((const i32x4*)&eli[p0]);
    i32x4 ea1 = __builtin_nontemporal_load((const i32x4*)&eli[p0 + 4]);
    i32x4 eb0 = __builtin_nontemporal_load((const i32x4*)&eli[ND + p0]);
    i32x4 eb1 = __builtin_nontemporal_load((const i32x4*)&eli[ND + p0 + 4]);
    int ia[8] = {ea0.x, ea0.y, ea0.z, ea0.w, ea1.x, ea1.y, ea1.z, ea1.w};
    int ib[8] = {eb0.x, eb0.y, eb0.z, eb0.w, eb1.x, eb1.y, eb1.z, eb1.w};
    float v[8];
#pragma unroll
    for (int q = 0; q < 8; ++q) {
        h16x8 va = *(const h16x8*)&z2[(size_t)ia[q] * DO + sub * 8];
        h16x8 vb = *(const h16x8*)&z2[(size_t)ib[q] * DO + sub * 8];
        float acc = 0.f;
#pragma unroll
        for (int k = 0; k < 8; ++k) acc += (float)va[k] * (float)vb[k];
        v[q] = acc;
    }
#pragma unroll
    for (int o = 1; o < 8; o <<= 1) {
#pragma unroll
        for (int q = 0; q < 8; ++q) v[q] += __shfl_xor(v[q], o);
    }
    if (sub == 0) {
        f32x4 r0 = (f32x4){v[0], v[1], v[2], v[3]};
        f32x4 r1 = (f32x4){v[4], v[5], v[6], v[7]};
        __builtin_nontemporal_store(r0, (f32x4*)&out[p0]);
        __builtin_nontemporal_store(r1, (f32x4*)&out[p0 + 4]);
    }
}

extern "C" void kernel_launch(void* const* d_in, const int* in_sizes, int n_in,
                              void* d_out, int out_size, void* d_ws, size_t ws_size,
                              hipStream_t stream) {
    const float* x  = (const float*)d_in[0];
    const float* Wi = (const float*)d_in[1];
    const float* bi = (const float*)d_in[2];
    const float* Wo = (const float*)d_in[3];
    const float* bo = (const float*)d_in[4];
    const int* ei   = (const int*)d_in[5];
    const int* eli  = (const int*)d_in[6];
    float* out = (float*)d_out;

    char* ws = (char*)d_ws;
    size_t o = 0;
    auto alloc = [&](size_t bytes) -> char* {
        char* p = ws + o;
        o = (o + bytes + 255) & ~(size_t)255;
        return p;
    };
    float* dinv = (float*)alloc(NN * 4);
    int* bcur   = (int*)alloc((NB + 1) * 4);   // bcur[NB] = global csrc cursor
    int* off    = (int*)alloc(NN * 4);
    int* degn   = (int*)alloc(NN * 4);
    int* bpk    = (int*)alloc((size_t)NB * BCAP * 4);
    u16* csrc   = (u16*)alloc(((size_t)NE + 2 * NB) * 2);
    h16* WiT    = (h16*)alloc(128 * 128 * 2);
    h16* WoT    = (h16*)alloc(64 * 128 * 2);
    h16* h1     = (h16*)alloc((size_t)NN * DH * 2);
    h16* z1     = (h16*)alloc((size_t)NN * DH * 2);
    h16* h2     = (h16*)alloc((size_t)NN * DO * 2);
    h16* z2     = (h16*)alloc((size_t)NN * DO * 2);

    const int* esrc = ei;
    const int* edst = ei + NE;

    hipMemsetAsync(bcur, 0, (NB + 1) * 4, stream);
    k_bucket_wt<<<P1B + WTB1, 1024, 0, stream>>>(esrc, edst, bpk, bcur, Wi, Wo, WiT, WoT);
    k_sort_gemm1<<<NB + GB1, 256, 0, stream>>>(bpk, bcur, &bcur[NB], off, degn,
                                               dinv, csrc, x, WiT, h1);
    k_agg128<<<(NN + 7) / 8, 256, 0, stream>>>((const h16x4*)h1, dinv, off, degn, csrc, bi, (h16x4*)z1);
    k_gemm2<<<GB1, 256, 0, stream>>>(z1, WoT, h2);
    k_agg64<<<(NN + 15) / 16, 256, 0, stream>>>((const h16x4*)h2, dinv, off, degn, csrc, bo, (h16x4*)z2);

    k_dec<<<(ND / 8 + 31) / 32, 256, 0, stream>>>(z2, eli, out);
}

// Round 15
// 110.624 us; speedup vs baseline: 1.0781x; 1.0781x over previous
//
#include <hip/hip_runtime.h>

#define NN 50000
#define NE 800000
#define ND 1000000
#define DH 128
#define DO 64

#define NB 196          // buckets: bucket = dst >> 8 (256 nodes each)
#define BCAP 5120       // per-bucket pass-1 capacity (mean 4096, 16 sigma)
#define SCAP 6400       // padded LDS staging capacity (4096 + 7*256 + slack)
#define P1B 196         // pass-1 edge blocks (1024 thr x 4 edges = 4096)
#define WTB1 25         // transpose blocks + sentinel-row zeroing
#define GB1 ((NN + 63) / 64)   // 782 gemm blocks

typedef _Float16 h16;
typedef h16 h16x4 __attribute__((ext_vector_type(4)));
typedef h16 h16x8 __attribute__((ext_vector_type(8)));
typedef float f32x4 __attribute__((ext_vector_type(4)));
typedef unsigned short u16;

// Pass 1: bucket edges by dst>>8 (packed src|dlow<<16) || W transpose ||
// zero the sentinel rows h1[NN], h2[NN] (gather pad target, weight 0).
__global__ __launch_bounds__(1024) void k_bucket_wt(
    const int* __restrict__ esrc, const int* __restrict__ edst,
    int* __restrict__ bpk, int* __restrict__ bcur,
    const float* __restrict__ Wi, const float* __restrict__ Wo,
    h16* __restrict__ WiT, h16* __restrict__ WoT,
    h16* __restrict__ h1, h16* __restrict__ h2) {
    if (blockIdx.x < P1B) {
        __shared__ int hist[NB], gbase[NB], lcur[NB];
        int t = threadIdx.x;
        if (t < NB) { hist[t] = 0; lcur[t] = 0; }
        __syncthreads();
        int base = blockIdx.x * 4096;
        int b[4], pk[4];
#pragma unroll
        for (int i = 0; i < 4; ++i) {
            int idx = base + t + i * 1024;
            if (idx < NE) {
                int s = esrc[idx];
                int d = edst[idx];
                b[i] = d >> 8;
                pk[i] = s | ((d & 255) << 16);
                atomicAdd(&hist[b[i]], 1);
            } else {
                b[i] = -1;
            }
        }
        __syncthreads();
        if (t < NB && hist[t] > 0) gbase[t] = atomicAdd(&bcur[t], hist[t]);
        __syncthreads();
#pragma unroll
        for (int i = 0; i < 4; ++i) {
            if (b[i] >= 0) {
                int r = atomicAdd(&lcur[b[i]], 1);
                bpk[b[i] * BCAP + gbase[b[i]] + r] = pk[i];
            }
        }
    } else {
        int t = (blockIdx.x - P1B) * 1024 + threadIdx.x;
        if (t < 128 * 128) {            // WiT[n][k] = Wi[k][n]
            int k = t >> 7, n = t & 127;
            WiT[n * 128 + k] = (h16)Wi[t];
        } else if (t < 128 * 128 + 64 * 128) {  // WoT[n][k] = Wo[k][n]
            int t2 = t - 128 * 128;
            int k = t2 >> 6, n = t2 & 63;
            WoT[n * 128 + k] = (h16)Wo[t2];
        } else if (t < 128 * 128 + 64 * 128 + 192) {
            int t3 = t - (128 * 128 + 64 * 128);
            if (t3 < 128) h1[(size_t)NN * DH + t3] = (h16)0.f;  // sentinel rows
            else          h2[(size_t)NN * DO + (t3 - 128)] = (h16)0.f;
        }
    }
}

// ---------------- MFMA GEMM body (NO dinv dependency) ----------------
template <int BN, bool AF32>
__device__ __forceinline__ void gemm_body(
    const void* __restrict__ Ain, const h16* __restrict__ WT,
    h16* __restrict__ out, int bx, char* sX, char* sW) {
    const int tid = threadIdx.x;
    const int row0 = bx * 64;

#pragma unroll
    for (int i = 0; i < 4; ++i) {
        int c = tid + i * 256;
        int row = c >> 4, kb = c & 15;
        int gr = row0 + row;
        h16x8 v = {};
        if (gr < NN) {
            if (AF32) {
                const float* src = (const float*)Ain + (size_t)gr * 128 + kb * 8;
                float4 u0 = *(const float4*)src;
                float4 u1 = *(const float4*)(src + 4);
                v[0] = (h16)u0.x; v[1] = (h16)u0.y; v[2] = (h16)u0.z; v[3] = (h16)u0.w;
                v[4] = (h16)u1.x; v[5] = (h16)u1.y; v[6] = (h16)u1.z; v[7] = (h16)u1.w;
            } else {
                v = *(const h16x8*)((const h16*)Ain + (size_t)gr * 128 + kb * 8);
            }
        }
        *(h16x8*)(sX + row * 256 + ((kb * 16) ^ ((row & 7) << 4))) = v;
    }
#pragma unroll
    for (int i = 0; i < BN / 16; ++i) {
        int c = tid + i * 256;
        int n = c >> 4, kb = c & 15;
        h16x8 v = *(const h16x8*)&WT[(size_t)n * 128 + kb * 8];
        *(h16x8*)(sW + n * 256 + ((kb * 16) ^ ((n & 7) << 4))) = v;
    }
    __syncthreads();

    const int lane = tid & 63, wv = tid >> 6;
    const int g = lane >> 4, l15 = lane & 15;
    const int r = wv * 16 + l15;
    f32x4 acc[BN / 16];
#pragma unroll
    for (int ct = 0; ct < BN / 16; ++ct) acc[ct] = (f32x4){0.f, 0.f, 0.f, 0.f};

#pragma unroll
    for (int t = 0; t < 4; ++t) {
        int kb2 = t * 64 + g * 16;
        h16x8 a = *(const h16x8*)(sX + r * 256 + (kb2 ^ ((r & 7) << 4)));
#pragma unroll
        for (int ct = 0; ct < BN / 16; ++ct) {
            int n = ct * 16 + l15;
            h16x8 b = *(const h16x8*)(sW + n * 256 + (kb2 ^ ((n & 7) << 4)));
            acc[ct] = __builtin_amdgcn_mfma_f32_16x16x32_f16(a, b, acc[ct], 0, 0, 0);
        }
    }

#pragma unroll
    for (int j = 0; j < 4; ++j) {
        int row = row0 + wv * 16 + g * 4 + j;
        if (row < NN) {
#pragma unroll
            for (int ct = 0; ct < BN / 16; ++ct)
                out[(size_t)row * BN + ct * 16 + l15] = (h16)acc[ct][j];
        }
    }
}

// Fused: {per-bucket counting sort with 8-padding (blocks 0..NB-1)} ||
// {gemm1 x*Wi unscaled}. Dep check: gemm reads {x,WiT} writes h1[<NN];
// sort reads {bpk,bcur} writes {off,degn,dinv,csrc}. Disjoint -> race-free.
__global__ __launch_bounds__(256) void k_sort_gemm1(
    const int* __restrict__ bpk, const int* __restrict__ bcur,
    int* __restrict__ gcur, int* __restrict__ off, int* __restrict__ degn,
    float* __restrict__ dinv, u16* __restrict__ csrc,
    const float* __restrict__ x, const h16* __restrict__ WiT,
    h16* __restrict__ h1) {
    __shared__ __align__(16) char smem[49152];
    if (blockIdx.x >= NB) {
        gemm_body<DH, true>(x, WiT, h1, blockIdx.x - NB, smem, smem + 16384);
        return;
    }
    int* hist = (int*)smem;          // 256
    int* lofs = hist + 256;          // 256
    int* exc  = lofs + 256;          // 256
    int* lcur = exc + 256;           // 256
    int* sgb  = lcur + 256;          // 1
    u16* scsr = (u16*)(sgb + 4);     // SCAP
    int b = blockIdx.x, t = threadIdx.x;
    hist[t] = 0; lcur[t] = 0;
    __syncthreads();
    int cnt = bcur[b];
    const int* bp = bpk + b * BCAP;
    for (int j = t; j < cnt; j += 256)
        atomicAdd(&hist[(bp[j] >> 16) & 255], 1);
    __syncthreads();
    int pd = (hist[t] + 7) & ~7;     // padded degree (multiple of 8)
    lofs[t] = pd;
    __syncthreads();
#pragma unroll
    for (int d = 1; d < 256; d <<= 1) {
        int add = (t >= d) ? lofs[t - d] : 0;
        __syncthreads();
        lofs[t] += add;
        __syncthreads();
    }
    exc[t] = lofs[t] - pd;
    __syncthreads();
    int cntp = lofs[255];            // total padded (multiple of 8)
    if (t == 0) *sgb = atomicAdd(gcur, cntp);
    // init staging to sentinel NN (weight dinv[NN]=0 -> exact no-op)
    for (int j = t; j < cntp; j += 256) scsr[j] = (u16)NN;
    __syncthreads();
    int gbase = *sgb;
    int node = b * 256 + t;
    if (node < NN) {
        off[node] = gbase + exc[t];
        degn[node] = pd;             // padded: agg loop is pure 8-wide
        dinv[node] = rsqrtf((float)hist[t] + 1.0f);  // true deg +1 self-loop
    }
    if (b == 0 && t == 0) dinv[NN] = 0.f;  // sentinel weight
    for (int j = t; j < cnt; j += 256) {
        int p = bp[j];
        int d = (p >> 16) & 255;
        int r = atomicAdd(&lcur[d], 1);
        scsr[exc[d] + r] = (u16)(p & 0xFFFF);
    }
    __syncthreads();
    u16* cdst = csrc + gbase;        // gbase multiple of 8 -> dword aligned
    for (int j = t; j < cntp / 2; j += 256)
        *(unsigned*)(cdst + 2 * j) = *(const unsigned*)(scsr + 2 * j);
}

__global__ __launch_bounds__(256) void k_gemm2(
    const h16* __restrict__ z1, const h16* __restrict__ WoT,
    h16* __restrict__ h2) {
    __shared__ __align__(16) char smem[32768];
    gemm_body<DO, false>(z1, WoT, h2, blockIdx.x, smem, smem + 16384);
}

// z1[n] = fp16(relu(dinv[n]*(sum dinv[s]*h1[s] + dinv[n]*h1[n]) + b))
// 32-lane group/node; padded csrc -> pure 8-wide loop, no tail.
__global__ __launch_bounds__(256) void k_agg128(
    const h16x4* __restrict__ hs, const float* __restrict__ dinv,
    const int* __restrict__ off, const int* __restrict__ degn,
    const u16* __restrict__ csrc,
    const float* __restrict__ bias, h16x4* __restrict__ z) {
    int node = blockIdx.x * 8 + (threadIdx.x >> 5);
    if (node >= NN) return;
    int col = threadIdx.x & 31;
    int s = off[node], e = s + degn[node];
    float a0 = 0.f, a1 = 0.f, a2 = 0.f, a3 = 0.f;
    for (int j = s; j < e; j += 8) {
        int i0 = csrc[j],     i1 = csrc[j + 1], i2 = csrc[j + 2], i3 = csrc[j + 3];
        int i4 = csrc[j + 4], i5 = csrc[j + 5], i6 = csrc[j + 6], i7 = csrc[j + 7];
        float w0 = dinv[i0], w1 = dinv[i1], w2 = dinv[i2], w3 = dinv[i3];
        float w4 = dinv[i4], w5 = dinv[i5], w6 = dinv[i6], w7 = dinv[i7];
        h16x4 v0 = hs[(size_t)i0 * 32 + col];
        h16x4 v1 = hs[(size_t)i1 * 32 + col];
        h16x4 v2 = hs[(size_t)i2 * 32 + col];
        h16x4 v3 = hs[(size_t)i3 * 32 + col];
        h16x4 v4 = hs[(size_t)i4 * 32 + col];
        h16x4 v5 = hs[(size_t)i5 * 32 + col];
        h16x4 v6 = hs[(size_t)i6 * 32 + col];
        h16x4 v7 = hs[(size_t)i7 * 32 + col];
        a0 = fmaf(w0, (float)v0.x, a0); a1 = fmaf(w0, (float)v0.y, a1);
        a2 = fmaf(w0, (float)v0.z, a2); a3 = fmaf(w0, (float)v0.w, a3);
        a0 = fmaf(w1, (float)v1.x, a0); a1 = fmaf(w1, (float)v1.y, a1);
        a2 = fmaf(w1, (float)v1.z, a2); a3 = fmaf(w1, (float)v1.w, a3);
        a0 = fmaf(w2, (float)v2.x, a0); a1 = fmaf(w2, (float)v2.y, a1);
        a2 = fmaf(w2, (float)v2.z, a2); a3 = fmaf(w2, (float)v2.w, a3);
        a0 = fmaf(w3, (float)v3.x, a0); a1 = fmaf(w3, (float)v3.y, a1);
        a2 = fmaf(w3, (float)v3.z, a2); a3 = fmaf(w3, (float)v3.w, a3);
        a0 = fmaf(w4, (float)v4.x, a0); a1 = fmaf(w4, (float)v4.y, a1);
        a2 = fmaf(w4, (float)v4.z, a2); a3 = fmaf(w4, (float)v4.w, a3);
        a0 = fmaf(w5, (float)v5.x, a0); a1 = fmaf(w5, (float)v5.y, a1);
        a2 = fmaf(w5, (float)v5.z, a2); a3 = fmaf(w5, (float)v5.w, a3);
        a0 = fmaf(w6, (float)v6.x, a0); a1 = fmaf(w6, (float)v6.y, a1);
        a2 = fmaf(w6, (float)v6.z, a2); a3 = fmaf(w6, (float)v6.w, a3);
        a0 = fmaf(w7, (float)v7.x, a0); a1 = fmaf(w7, (float)v7.y, a1);
        a2 = fmaf(w7, (float)v7.z, a2); a3 = fmaf(w7, (float)v7.w, a3);
    }
    float dv = dinv[node];
    h16x4 vs = hs[(size_t)node * 32 + col];  // self loop
    a0 = fmaf(dv, (float)vs.x, a0); a1 = fmaf(dv, (float)vs.y, a1);
    a2 = fmaf(dv, (float)vs.z, a2); a3 = fmaf(dv, (float)vs.w, a3);
    float4 bb = ((const float4*)bias)[col];
    float r0 = dv * a0 + bb.x, r1 = dv * a1 + bb.y;
    float r2 = dv * a2 + bb.z, r3 = dv * a3 + bb.w;
    h16x4 o;
    o.x = (h16)(r0 > 0.f ? r0 : 0.f); o.y = (h16)(r1 > 0.f ? r1 : 0.f);
    o.z = (h16)(r2 > 0.f ? r2 : 0.f); o.w = (h16)(r3 > 0.f ? r3 : 0.f);
    z[(size_t)node * 32 + col] = o;
}

// z2[n] = fp16(relu(...)); 16-lane group/node; padded -> no tail.
__global__ __launch_bounds__(256) void k_agg64(
    const h16x4* __restrict__ hs, const float* __restrict__ dinv,
    const int* __restrict__ off, const int* __restrict__ degn,
    const u16* __restrict__ csrc,
    const float* __restrict__ bias, h16x4* __restrict__ z) {
    int node = blockIdx.x * 16 + (threadIdx.x >> 4);
    if (node >= NN) return;
    int col = threadIdx.x & 15;
    int s = off[node], e = s + degn[node];
    float a0 = 0.f, a1 = 0.f, a2 = 0.f, a3 = 0.f;
    for (int j = s; j < e; j += 8) {
        int i0 = csrc[j],     i1 = csrc[j + 1], i2 = csrc[j + 2], i3 = csrc[j + 3];
        int i4 = csrc[j + 4], i5 = csrc[j + 5], i6 = csrc[j + 6], i7 = csrc[j + 7];
        float w0 = dinv[i0], w1 = dinv[i1], w2 = dinv[i2], w3 = dinv[i3];
        float w4 = dinv[i4], w5 = dinv[i5], w6 = dinv[i6], w7 = dinv[i7];
        h16x4 v0 = hs[(size_t)i0 * 16 + col];
        h16x4 v1 = hs[(size_t)i1 * 16 + col];
        h16x4 v2 = hs[(size_t)i2 * 16 + col];
        h16x4 v3 = hs[(size_t)i3 * 16 + col];
        h16x4 v4 = hs[(size_t)i4 * 16 + col];
        h16x4 v5 = hs[(size_t)i5 * 16 + col];
        h16x4 v6 = hs[(size_t)i6 * 16 + col];
        h16x4 v7 = hs[(size_t)i7 * 16 + col];
        a0 = fmaf(w0, (float)v0.x, a0); a1 = fmaf(w0, (float)v0.y, a1);
        a2 = fmaf(w0, (float)v0.z, a2); a3 = fmaf(w0, (float)v0.w, a3);
        a0 = fmaf(w1, (float)v1.x, a0); a1 = fmaf(w1, (float)v1.y, a1);
        a2 = fmaf(w1, (float)v1.z, a2); a3 = fmaf(w1, (float)v1.w, a3);
        a0 = fmaf(w2, (float)v2.x, a0); a1 = fmaf(w2, (float)v2.y, a1);
        a2 = fmaf(w2, (float)v2.z, a2); a3 = fmaf(w2, (float)v2.w, a3);
        a0 = fmaf(w3, (float)v3.x, a0); a1 = fmaf(w3, (float)v3.y, a1);
        a2 = fmaf(w3, (float)v3.z, a2); a3 = fmaf(w3, (float)v3.w, a3);
        a0 = fmaf(w4, (float)v4.x, a0); a1 = fmaf(w4, (float)v4.y, a1);
        a2 = fmaf(w4, (float)v4.z, a2); a3 = fmaf(w4, (float)v4.w, a3);
        a0 = fmaf(w5, (float)v5.x, a0); a1 = fmaf(w5, (float)v5.y, a1);
        a2 = fmaf(w5, (float)v5.z, a2); a3 = fmaf(w5, (float)v5.w, a3);
        a0 = fmaf(w6, (float)v6.x, a0); a1 = fmaf(w6, (float)v6.y, a1);
        a2 = fmaf(w6, (float)v6.z, a2); a3 = fmaf(w6, (float)v6.w, a3);
        a0 = fmaf(w7, (float)v7.x, a0); a1 = fmaf(w7, (float)v7.y, a1);
        a2 = fmaf(w7, (float)v7.z, a2); a3 = fmaf(w7, (float)v7.w, a3);
    }
    float dv = dinv[node];
    h16x4 vs = hs[(size_t)node * 16 + col];  // self loop
    a0 = fmaf(dv, (float)vs.x, a0); a1 = fmaf(dv, (float)vs.y, a1);
    a2 = fmaf(dv, (float)vs.z, a2); a3 = fmaf(dv, (float)vs.w, a3);
    float4 bb = ((const float4*)bias)[col];
    float r0 = dv * a0 + bb.x, r1 = dv * a1 + bb.y;
    float r2 = dv * a2 + bb.z, r3 = dv * a3 + bb.w;
    h16x4 o;
    o.x = (h16)(r0 > 0.f ? r0 : 0.f); o.y = (h16)(r1 > 0.f ? r1 : 0.f);
    o.z = (h16)(r2 > 0.f ? r2 : 0.f); o.w = (h16)(r3 > 0.f ? r3 : 0.f);
    z[(size_t)node * 16 + col] = o;
}

// 8-lane groups, h16x8 (16B) loads, 8 pairs/group, int4 eli loads.
__global__ __launch_bounds__(256) void k_dec(const h16* __restrict__ z2,
                                             const int* __restrict__ eli,
                                             float* __restrict__ out) {
    int g = blockIdx.x * 32 + (threadIdx.x >> 3);
    int p0 = g * 8;
    if (p0 >= ND) return;
    int sub = threadIdx.x & 7;
    int4 ea0 = *(const int4*)&eli[p0];
    int4 ea1 = *(const int4*)&eli[p0 + 4];
    int4 eb0 = *(const int4*)&eli[ND + p0];
    int4 eb1 = *(const int4*)&eli[ND + p0 + 4];
    int ia[8] = {ea0.x, ea0.y, ea0.z, ea0.w, ea1.x, ea1.y, ea1.z, ea1.w};
    int ib[8] = {eb0.x, eb0.y, eb0.z, eb0.w, eb1.x, eb1.y, eb1.z, eb1.w};
    float v[8];
#pragma unroll
    for (int q = 0; q < 8; ++q) {
        h16x8 va = *(const h16x8*)&z2[(size_t)ia[q] * DO + sub * 8];
        h16x8 vb = *(const h16x8*)&z2[(size_t)ib[q] * DO + sub * 8];
        float acc = 0.f;
#pragma unroll
        for (int k = 0; k < 8; ++k) acc += (float)va[k] * (float)vb[k];
        v[q] = acc;
    }
#pragma unroll
    for (int o = 1; o < 8; o <<= 1) {
#pragma unroll
        for (int q = 0; q < 8; ++q) v[q] += __shfl_xor(v[q], o);
    }
    if (sub == 0) {
        *(float4*)&out[p0] = make_float4(v[0], v[1], v[2], v[3]);
        *(float4*)&out[p0 + 4] = make_float4(v[4], v[5], v[6], v[7]);
    }
}

extern "C" void kernel_launch(void* const* d_in, const int* in_sizes, int n_in,
                              void* d_out, int out_size, void* d_ws, size_t ws_size,
                              hipStream_t stream) {
    const float* x  = (const float*)d_in[0];
    const float* Wi = (const float*)d_in[1];
    const float* bi = (const float*)d_in[2];
    const float* Wo = (const float*)d_in[3];
    const float* bo = (const float*)d_in[4];
    const int* ei   = (const int*)d_in[5];
    const int* eli  = (const int*)d_in[6];
    float* out = (float*)d_out;

    char* ws = (char*)d_ws;
    size_t o = 0;
    auto alloc = [&](size_t bytes) -> char* {
        char* p = ws + o;
        o = (o + bytes + 255) & ~(size_t)255;
        return p;
    };
    float* dinv = (float*)alloc((NN + 1) * 4);        // +1 sentinel weight 0
    int* bcur   = (int*)alloc((NB + 1) * 4);          // bcur[NB] = csrc cursor
    int* off    = (int*)alloc(NN * 4);
    int* degn   = (int*)alloc(NN * 4);
    int* bpk    = (int*)alloc((size_t)NB * BCAP * 4);
    u16* csrc   = (u16*)alloc(((size_t)NE + 8 * NN + 64) * 2);  // padded
    h16* WiT    = (h16*)alloc(128 * 128 * 2);
    h16* WoT    = (h16*)alloc(64 * 128 * 2);
    h16* h1     = (h16*)alloc((size_t)(NN + 1) * DH * 2);  // +sentinel row
    h16* z1     = (h16*)alloc((size_t)NN * DH * 2);
    h16* h2     = (h16*)alloc((size_t)(NN + 1) * DO * 2);  // +sentinel row
    h16* z2     = (h16*)alloc((size_t)NN * DO * 2);

    const int* esrc = ei;
    const int* edst = ei + NE;

    hipMemsetAsync(bcur, 0, (NB + 1) * 4, stream);
    k_bucket_wt<<<P1B + WTB1, 1024, 0, stream>>>(esrc, edst, bpk, bcur, Wi, Wo,
                                                 WiT, WoT, h1, h2);
    k_sort_gemm1<<<NB + GB1, 256, 0, stream>>>(bpk, bcur, &bcur[NB], off, degn,
                                               dinv, csrc, x, WiT, h1);
    k_agg128<<<(NN + 7) / 8, 256, 0, stream>>>((const h16x4*)h1, dinv, off, degn, csrc, bi, (h16x4*)z1);
    k_gemm2<<<GB1, 256, 0, stream>>>(z1, WoT, h2);
    k_agg64<<<(NN + 15) / 16, 256, 0, stream>>>((const h16x4*)h2, dinv, off, degn, csrc, bo, (h16x4*)z2);

    k_dec<<<(ND / 8 + 31) / 32, 256, 0, stream>>>(z2, eli, out);
}

// Round 16
// 95.924 us; speedup vs baseline: 1.2433x; 1.1533x over previous
//
#include <hip/hip_runtime.h>

#define NN 50000
#define NE 800000
#define ND 1000000
#define DH 128
#define DO 64

#define NB 196          // buckets: bucket = dst >> 8 (256 nodes each)
#define BCAPP 6400      // per-bucket padded csrc capacity (mult of 8)
#define P1B 196         // pass-1 edge blocks (1024 thr x 4 edges = 4096)
#define WTB1 25         // transpose blocks + sentinel-row zeroing
#define GB1 ((NN + 63) / 64)   // 782 gemm blocks

typedef _Float16 h16;
typedef h16 h16x4 __attribute__((ext_vector_type(4)));
typedef h16 h16x8 __attribute__((ext_vector_type(8)));
typedef float f32x4 __attribute__((ext_vector_type(4)));
typedef unsigned short u16;

// Pass 1: bucket edges into fixed per-(bucket,block) chunks — NO global
// atomics, NO memset needed. || W transpose || sentinel-row zeroing.
__global__ __launch_bounds__(1024) void k_bucket_wt(
    const int* __restrict__ esrc, const int* __restrict__ edst,
    int* __restrict__ bpk, int* __restrict__ cnt,
    const float* __restrict__ Wi, const float* __restrict__ Wo,
    h16* __restrict__ WiT, h16* __restrict__ WoT,
    h16* __restrict__ h1, h16* __restrict__ h2) {
    if (blockIdx.x < P1B) {
        __shared__ int lcur[NB];
        int t = threadIdx.x;
        if (t < NB) lcur[t] = 0;
        __syncthreads();
        int base = blockIdx.x * 4096;
#pragma unroll
        for (int i = 0; i < 4; ++i) {
            int idx = base + t + i * 1024;
            if (idx < NE) {
                int s = esrc[idx];
                int d = edst[idx];
                int bb = d >> 8;
                int r = atomicAdd(&lcur[bb], 1);     // LDS only
                bpk[((size_t)bb * P1B + blockIdx.x) * 64 + r] =
                    s | ((d & 255) << 16);
            }
        }
        __syncthreads();
        if (t < NB) cnt[blockIdx.x * NB + t] = lcur[t];
    } else {
        int t = (blockIdx.x - P1B) * 1024 + threadIdx.x;
        if (t < 128 * 128) {            // WiT[n][k] = Wi[k][n]
            int k = t >> 7, n = t & 127;
            WiT[n * 128 + k] = (h16)Wi[t];
        } else if (t < 128 * 128 + 64 * 128) {  // WoT[n][k] = Wo[k][n]
            int t2 = t - 128 * 128;
            int k = t2 >> 6, n = t2 & 63;
            WoT[n * 128 + k] = (h16)Wo[t2];
        } else if (t < 128 * 128 + 64 * 128 + 192) {
            int t3 = t - (128 * 128 + 64 * 128);
            if (t3 < 128) h1[(size_t)NN * DH + t3] = (h16)0.f;  // sentinel
            else          h2[(size_t)NN * DO + (t3 - 128)] = (h16)0.f;
        }
    }
}

// ---------------- MFMA GEMM body (NO dinv dependency) ----------------
template <int BN, bool AF32>
__device__ __forceinline__ void gemm_body(
    const void* __restrict__ Ain, const h16* __restrict__ WT,
    h16* __restrict__ out, int bx, char* sX, char* sW) {
    const int tid = threadIdx.x;
    const int row0 = bx * 64;

#pragma unroll
    for (int i = 0; i < 4; ++i) {
        int c = tid + i * 256;
        int row = c >> 4, kb = c & 15;
        int gr = row0 + row;
        h16x8 v = {};
        if (gr < NN) {
            if (AF32) {
                const float* src = (const float*)Ain + (size_t)gr * 128 + kb * 8;
                float4 u0 = *(const float4*)src;
                float4 u1 = *(const float4*)(src + 4);
                v[0] = (h16)u0.x; v[1] = (h16)u0.y; v[2] = (h16)u0.z; v[3] = (h16)u0.w;
                v[4] = (h16)u1.x; v[5] = (h16)u1.y; v[6] = (h16)u1.z; v[7] = (h16)u1.w;
            } else {
                v = *(const h16x8*)((const h16*)Ain + (size_t)gr * 128 + kb * 8);
            }
        }
        *(h16x8*)(sX + row * 256 + ((kb * 16) ^ ((row & 7) << 4))) = v;
    }
#pragma unroll
    for (int i = 0; i < BN / 16; ++i) {
        int c = tid + i * 256;
        int n = c >> 4, kb = c & 15;
        h16x8 v = *(const h16x8*)&WT[(size_t)n * 128 + kb * 8];
        *(h16x8*)(sW + n * 256 + ((kb * 16) ^ ((n & 7) << 4))) = v;
    }
    __syncthreads();

    const int lane = tid & 63, wv = tid >> 6;
    const int g = lane >> 4, l15 = lane & 15;
    const int r = wv * 16 + l15;
    f32x4 acc[BN / 16];
#pragma unroll
    for (int ct = 0; ct < BN / 16; ++ct) acc[ct] = (f32x4){0.f, 0.f, 0.f, 0.f};

#pragma unroll
    for (int t = 0; t < 4; ++t) {
        int kb2 = t * 64 + g * 16;
        h16x8 a = *(const h16x8*)(sX + r * 256 + (kb2 ^ ((r & 7) << 4)));
#pragma unroll
        for (int ct = 0; ct < BN / 16; ++ct) {
            int n = ct * 16 + l15;
            h16x8 b = *(const h16x8*)(sW + n * 256 + (kb2 ^ ((n & 7) << 4)));
            acc[ct] = __builtin_amdgcn_mfma_f32_16x16x32_f16(a, b, acc[ct], 0, 0, 0);
        }
    }

#pragma unroll
    for (int j = 0; j < 4; ++j) {
        int row = row0 + wv * 16 + g * 4 + j;
        if (row < NN) {
#pragma unroll
            for (int ct = 0; ct < BN / 16; ++ct)
                out[(size_t)row * BN + ct * 16 + l15] = (h16)acc[ct][j];
        }
    }
}

// Fused: {per-bucket counting sort with 8-padding (blocks 0..NB-1)} ||
// {gemm1}. Dep check: gemm reads {x,WiT}, writes h1[<NN]; sort reads
// {bpk,cnt}, writes {off,degn,dinv,csrc}. Disjoint -> race-free.
__global__ __launch_bounds__(256) void k_sort_gemm1(
    const int* __restrict__ bpk, const int* __restrict__ cnt,
    int* __restrict__ off, int* __restrict__ degn,
    float* __restrict__ dinv, u16* __restrict__ csrc,
    const float* __restrict__ x, const h16* __restrict__ WiT,
    h16* __restrict__ h1) {
    __shared__ __align__(16) char smem[49152];
    if (blockIdx.x >= NB) {
        gemm_body<DH, true>(x, WiT, h1, blockIdx.x - NB, smem, smem + 16384);
        return;
    }
    int* hist   = (int*)smem;            // 256
    int* lofs   = hist + 256;            // 256
    int* exc    = lofs + 256;            // 256
    int* lcur   = exc + 256;             // 256
    int* cbs    = lcur + 256;            // 256
    int* scsr32 = cbs + 256;             // 5120 ints (raw bucket max ~4400)
    u16* scsr16 = (u16*)(scsr32 + 5120); // 6400 u16
    int b = blockIdx.x, t = threadIdx.x;
    hist[t] = 0; lcur[t] = 0;
    int cc = (t < P1B) ? cnt[t * NB + b] : 0;
    cbs[t] = cc;
    __syncthreads();
#pragma unroll
    for (int d = 1; d < 256; d <<= 1) {
        int add = (t >= d) ? cbs[t - d] : 0;
        __syncthreads();
        cbs[t] += add;
        __syncthreads();
    }
    int cbase = cbs[t] - cc;             // exclusive chunk base
    int craw = cbs[255];                 // raw edges in this bucket
    if (t < P1B) {                       // copy own chunk into LDS
        const int* src = bpk + ((size_t)b * P1B + t) * 64;
        for (int i = 0; i < cc; ++i) scsr32[cbase + i] = src[i];
    }
    __syncthreads();
    for (int j = t; j < craw; j += 256)
        atomicAdd(&hist[(scsr32[j] >> 16) & 255], 1);
    __syncthreads();
    int pd = (hist[t] + 7) & ~7;         // padded degree (multiple of 8)
    lofs[t] = pd;
    __syncthreads();
#pragma unroll
    for (int d = 1; d < 256; d <<= 1) {
        int add = (t >= d) ? lofs[t - d] : 0;
        __syncthreads();
        lofs[t] += add;
        __syncthreads();
    }
    exc[t] = lofs[t] - pd;
    __syncthreads();
    int cntp = lofs[255];                // padded total (<= BCAPP)
    for (int j = t; j < cntp; j += 256) scsr16[j] = (u16)NN;  // sentinel init
    __syncthreads();
    int node = b * 256 + t;
    if (node < NN) {
        off[node] = b * BCAPP + exc[t];
        degn[node] = pd;
        dinv[node] = rsqrtf((float)hist[t] + 1.0f);  // true deg +1 self-loop
    }
    if (b == 0 && t == 0) dinv[NN] = 0.f;            // sentinel weight
    for (int j = t; j < craw; j += 256) {
        int p = scsr32[j];
        int d = (p >> 16) & 255;
        int r = atomicAdd(&lcur[d], 1);
        scsr16[exc[d] + r] = (u16)(p & 0xFFFF);
    }
    __syncthreads();
    u16* cdst = csrc + (size_t)b * BCAPP;
    for (int j = t; j < cntp / 2; j += 256)
        *(unsigned*)(cdst + 2 * j) = *(const unsigned*)(scsr16 + 2 * j);
}

__global__ __launch_bounds__(256) void k_gemm2(
    const h16* __restrict__ z1, const h16* __restrict__ WoT,
    h16* __restrict__ h2) {
    __shared__ __align__(16) char smem[32768];
    gemm_body<DO, false>(z1, WoT, h2, blockIdx.x, smem, smem + 16384);
}

// z1[n] = fp16(relu(dinv[n]*(sum dinv[s]*h1[s] + dinv[n]*h1[n]) + b))
// 32-lane group/node; padded csrc -> pure 8-wide loop, no tail.
__global__ __launch_bounds__(256) void k_agg128(
    const h16x4* __restrict__ hs, const float* __restrict__ dinv,
    const int* __restrict__ off, const int* __restrict__ degn,
    const u16* __restrict__ csrc,
    const float* __restrict__ bias, h16x4* __restrict__ z) {
    int node = blockIdx.x * 8 + (threadIdx.x >> 5);
    if (node >= NN) return;
    int col = threadIdx.x & 31;
    int s = off[node], e = s + degn[node];
    float a0 = 0.f, a1 = 0.f, a2 = 0.f, a3 = 0.f;
    for (int j = s; j < e; j += 8) {
        int i0 = csrc[j],     i1 = csrc[j + 1], i2 = csrc[j + 2], i3 = csrc[j + 3];
        int i4 = csrc[j + 4], i5 = csrc[j + 5], i6 = csrc[j + 6], i7 = csrc[j + 7];
        float w0 = dinv[i0], w1 = dinv[i1], w2 = dinv[i2], w3 = dinv[i3];
        float w4 = dinv[i4], w5 = dinv[i5], w6 = dinv[i6], w7 = dinv[i7];
        h16x4 v0 = hs[(size_t)i0 * 32 + col];
        h16x4 v1 = hs[(size_t)i1 * 32 + col];
        h16x4 v2 = hs[(size_t)i2 * 32 + col];
        h16x4 v3 = hs[(size_t)i3 * 32 + col];
        h16x4 v4 = hs[(size_t)i4 * 32 + col];
        h16x4 v5 = hs[(size_t)i5 * 32 + col];
        h16x4 v6 = hs[(size_t)i6 * 32 + col];
        h16x4 v7 = hs[(size_t)i7 * 32 + col];
        a0 = fmaf(w0, (float)v0.x, a0); a1 = fmaf(w0, (float)v0.y, a1);
        a2 = fmaf(w0, (float)v0.z, a2); a3 = fmaf(w0, (float)v0.w, a3);
        a0 = fmaf(w1, (float)v1.x, a0); a1 = fmaf(w1, (float)v1.y, a1);
        a2 = fmaf(w1, (float)v1.z, a2); a3 = fmaf(w1, (float)v1.w, a3);
        a0 = fmaf(w2, (float)v2.x, a0); a1 = fmaf(w2, (float)v2.y, a1);
        a2 = fmaf(w2, (float)v2.z, a2); a3 = fmaf(w2, (float)v2.w, a3);
        a0 = fmaf(w3, (float)v3.x, a0); a1 = fmaf(w3, (float)v3.y, a1);
        a2 = fmaf(w3, (float)v3.z, a2); a3 = fmaf(w3, (float)v3.w, a3);
        a0 = fmaf(w4, (float)v4.x, a0); a1 = fmaf(w4, (float)v4.y, a1);
        a2 = fmaf(w4, (float)v4.z, a2); a3 = fmaf(w4, (float)v4.w, a3);
        a0 = fmaf(w5, (float)v5.x, a0); a1 = fmaf(w5, (float)v5.y, a1);
        a2 = fmaf(w5, (float)v5.z, a2); a3 = fmaf(w5, (float)v5.w, a3);
        a0 = fmaf(w6, (float)v6.x, a0); a1 = fmaf(w6, (float)v6.y, a1);
        a2 = fmaf(w6, (float)v6.z, a2); a3 = fmaf(w6, (float)v6.w, a3);
        a0 = fmaf(w7, (float)v7.x, a0); a1 = fmaf(w7, (float)v7.y, a1);
        a2 = fmaf(w7, (float)v7.z, a2); a3 = fmaf(w7, (float)v7.w, a3);
    }
    float dv = dinv[node];
    h16x4 vs = hs[(size_t)node * 32 + col];  // self loop
    a0 = fmaf(dv, (float)vs.x, a0); a1 = fmaf(dv, (float)vs.y, a1);
    a2 = fmaf(dv, (float)vs.z, a2); a3 = fmaf(dv, (float)vs.w, a3);
    float4 bb = ((const float4*)bias)[col];
    float r0 = dv * a0 + bb.x, r1 = dv * a1 + bb.y;
    float r2 = dv * a2 + bb.z, r3 = dv * a3 + bb.w;
    h16x4 o;
    o.x = (h16)(r0 > 0.f ? r0 : 0.f); o.y = (h16)(r1 > 0.f ? r1 : 0.f);
    o.z = (h16)(r2 > 0.f ? r2 : 0.f); o.w = (h16)(r3 > 0.f ? r3 : 0.f);
    z[(size_t)node * 32 + col] = o;
}

// z2[n] = fp16(relu(...)); 16-lane group/node; padded -> no tail.
__global__ __launch_bounds__(256) void k_agg64(
    const h16x4* __restrict__ hs, const float* __restrict__ dinv,
    const int* __restrict__ off, const int* __restrict__ degn,
    const u16* __restrict__ csrc,
    const float* __restrict__ bias, h16x4* __restrict__ z) {
    int node = blockIdx.x * 16 + (threadIdx.x >> 4);
    if (node >= NN) return;
    int col = threadIdx.x & 15;
    int s = off[node], e = s + degn[node];
    float a0 = 0.f, a1 = 0.f, a2 = 0.f, a3 = 0.f;
    for (int j = s; j < e; j += 8) {
        int i0 = csrc[j],     i1 = csrc[j + 1], i2 = csrc[j + 2], i3 = csrc[j + 3];
        int i4 = csrc[j + 4], i5 = csrc[j + 5], i6 = csrc[j + 6], i7 = csrc[j + 7];
        float w0 = dinv[i0], w1 = dinv[i1], w2 = dinv[i2], w3 = dinv[i3];
        float w4 = dinv[i4], w5 = dinv[i5], w6 = dinv[i6], w7 = dinv[i7];
        h16x4 v0 = hs[(size_t)i0 * 16 + col];
        h16x4 v1 = hs[(size_t)i1 * 16 + col];
        h16x4 v2 = hs[(size_t)i2 * 16 + col];
        h16x4 v3 = hs[(size_t)i3 * 16 + col];
        h16x4 v4 = hs[(size_t)i4 * 16 + col];
        h16x4 v5 = hs[(size_t)i5 * 16 + col];
        h16x4 v6 = hs[(size_t)i6 * 16 + col];
        h16x4 v7 = hs[(size_t)i7 * 16 + col];
        a0 = fmaf(w0, (float)v0.x, a0); a1 = fmaf(w0, (float)v0.y, a1);
        a2 = fmaf(w0, (float)v0.z, a2); a3 = fmaf(w0, (float)v0.w, a3);
        a0 = fmaf(w1, (float)v1.x, a0); a1 = fmaf(w1, (float)v1.y, a1);
        a2 = fmaf(w1, (float)v1.z, a2); a3 = fmaf(w1, (float)v1.w, a3);
        a0 = fmaf(w2, (float)v2.x, a0); a1 = fmaf(w2, (float)v2.y, a1);
        a2 = fmaf(w2, (float)v2.z, a2); a3 = fmaf(w2, (float)v2.w, a3);
        a0 = fmaf(w3, (float)v3.x, a0); a1 = fmaf(w3, (float)v3.y, a1);
        a2 = fmaf(w3, (float)v3.z, a2); a3 = fmaf(w3, (float)v3.w, a3);
        a0 = fmaf(w4, (float)v4.x, a0); a1 = fmaf(w4, (float)v4.y, a1);
        a2 = fmaf(w4, (float)v4.z, a2); a3 = fmaf(w4, (float)v4.w, a3);
        a0 = fmaf(w5, (float)v5.x, a0); a1 = fmaf(w5, (float)v5.y, a1);
        a2 = fmaf(w5, (float)v5.z, a2); a3 = fmaf(w5, (float)v5.w, a3);
        a0 = fmaf(w6, (float)v6.x, a0); a1 = fmaf(w6, (float)v6.y, a1);
        a2 = fmaf(w6, (float)v6.z, a2); a3 = fmaf(w6, (float)v6.w, a3);
        a0 = fmaf(w7, (float)v7.x, a0); a1 = fmaf(w7, (float)v7.y, a1);
        a2 = fmaf(w7, (float)v7.z, a2); a3 = fmaf(w7, (float)v7.w, a3);
    }
    float dv = dinv[node];
    h16x4 vs = hs[(size_t)node * 16 + col];  // self loop
    a0 = fmaf(dv, (float)vs.x, a0); a1 = fmaf(dv, (float)vs.y, a1);
    a2 = fmaf(dv, (float)vs.z, a2); a3 = fmaf(dv, (float)vs.w, a3);
    float4 bb = ((const float4*)bias)[col];
    float r0 = dv * a0 + bb.x, r1 = dv * a1 + bb.y;
    float r2 = dv * a2 + bb.z, r3 = dv * a3 + bb.w;
    h16x4 o;
    o.x = (h16)(r0 > 0.f ? r0 : 0.f); o.y = (h16)(r1 > 0.f ? r1 : 0.f);
    o.z = (h16)(r2 > 0.f ? r2 : 0.f); o.w = (h16)(r3 > 0.f ? r3 : 0.f);
    z[(size_t)node * 16 + col] = o;
}

// 8-lane groups, h16x8 (16B) loads, 8 pairs/group, int4 eli loads.
__global__ __launch_bounds__(256) void k_dec(const h16* __restrict__ z2,
                                             const int* __restrict__ eli,
                                             float* __restrict__ out) {
    int g = blockIdx.x * 32 + (threadIdx.x >> 3);
    int p0 = g * 8;
    if (p0 >= ND) return;
    int sub = threadIdx.x & 7;
    int4 ea0 = *(const int4*)&eli[p0];
    int4 ea1 = *(const int4*)&eli[p0 + 4];
    int4 eb0 = *(const int4*)&eli[ND + p0];
    int4 eb1 = *(const int4*)&eli[ND + p0 + 4];
    int ia[8] = {ea0.x, ea0.y, ea0.z, ea0.w, ea1.x, ea1.y, ea1.z, ea1.w};
    int ib[8] = {eb0.x, eb0.y, eb0.z, eb0.w, eb1.x, eb1.y, eb1.z, eb1.w};
    float v[8];
#pragma unroll
    for (int q = 0; q < 8; ++q) {
        h16x8 va = *(const h16x8*)&z2[(size_t)ia[q] * DO + sub * 8];
        h16x8 vb = *(const h16x8*)&z2[(size_t)ib[q] * DO + sub * 8];
        float acc = 0.f;
#pragma unroll
        for (int k = 0; k < 8; ++k) acc += (float)va[k] * (float)vb[k];
        v[q] = acc;
    }
#pragma unroll
    for (int o = 1; o < 8; o <<= 1) {
#pragma unroll
        for (int q = 0; q < 8; ++q) v[q] += __shfl_xor(v[q], o);
    }
    if (sub == 0) {
        *(float4*)&out[p0] = make_float4(v[0], v[1], v[2], v[3]);
        *(float4*)&out[p0 + 4] = make_float4(v[4], v[5], v[6], v[7]);
    }
}

extern "C" void kernel_launch(void* const* d_in, const int* in_sizes, int n_in,
                              void* d_out, int out_size, void* d_ws, size_t ws_size,
                              hipStream_t stream) {
    const float* x  = (const float*)d_in[0];
    const float* Wi = (const float*)d_in[1];
    const float* bi = (const float*)d_in[2];
    const float* Wo = (const float*)d_in[3];
    const float* bo = (const float*)d_in[4];
    const int* ei   = (const int*)d_in[5];
    const int* eli  = (const int*)d_in[6];
    float* out = (float*)d_out;

    char* ws = (char*)d_ws;
    size_t o = 0;
    auto alloc = [&](size_t bytes) -> char* {
        char* p = ws + o;
        o = (o + bytes + 255) & ~(size_t)255;
        return p;
    };
    float* dinv = (float*)alloc((NN + 1) * 4);        // +1 sentinel weight 0
    int* off    = (int*)alloc(NN * 4);
    int* degn   = (int*)alloc(NN * 4);
    int* cnt    = (int*)alloc((size_t)P1B * NB * 4);  // per-(block,bucket)
    int* bpk    = (int*)alloc((size_t)NB * P1B * 64 * 4);
    u16* csrc   = (u16*)alloc((size_t)NB * BCAPP * 2);
    h16* WiT    = (h16*)alloc(128 * 128 * 2);
    h16* WoT    = (h16*)alloc(64 * 128 * 2);
    h16* h1     = (h16*)alloc((size_t)(NN + 1) * DH * 2);  // +sentinel row
    h16* z1     = (h16*)alloc((size_t)NN * DH * 2);
    h16* h2     = (h16*)alloc((size_t)(NN + 1) * DO * 2);  // +sentinel row
    h16* z2     = (h16*)alloc((size_t)NN * DO * 2);

    const int* esrc = ei;
    const int* edst = ei + NE;

    k_bucket_wt<<<P1B + WTB1, 1024, 0, stream>>>(esrc, edst, bpk, cnt, Wi, Wo,
                                                 WiT, WoT, h1, h2);
    k_sort_gemm1<<<NB + GB1, 256, 0, stream>>>(bpk, cnt, off, degn,
                                               dinv, csrc, x, WiT, h1);
    k_agg128<<<(NN + 7) / 8, 256, 0, stream>>>((const h16x4*)h1, dinv, off, degn, csrc, bi, (h16x4*)z1);
    k_gemm2<<<GB1, 256, 0, stream>>>(z1, WoT, h2);
    k_agg64<<<(NN + 15) / 16, 256, 0, stream>>>((const h16x4*)h2, dinv, off, degn, csrc, bo, (h16x4*)z2);

    k_dec<<<(ND / 8 + 31) / 32, 256, 0, stream>>>(z2, eli, out);
}